// Round 4
// baseline (107.467 us; speedup 1.0000x reference)
//
#include <hip/hip_runtime.h>
#include <hip/hip_bf16.h>

#define SEQ 4096
#define DIM 512
#define SCALE 0.044194173824159216f  // 1/sqrt(512)

#define SPLITS 4
#define BQ 32
#define KVBLK 32
#define KEYS_PER_SPLIT (SEQ / SPLITS)    // 1024
#define ITERS (KEYS_PER_SPLIT / KVBLK)   // 32

typedef __attribute__((ext_vector_type(8))) short short8;
typedef __attribute__((ext_vector_type(4))) float f32x4;

__device__ __forceinline__ short f2bf(float f) {
  union { float f; unsigned u; } c; c.f = f;
  unsigned u = c.u;
  return (short)((u + 0x7FFFu + ((u >> 16) & 1u)) >> 16);
}

__device__ __forceinline__ short8 pack8(float4 a, float4 b) {
  short8 r;
  r[0] = f2bf(a.x); r[1] = f2bf(a.y); r[2] = f2bf(a.z); r[3] = f2bf(a.w);
  r[4] = f2bf(b.x); r[5] = f2bf(b.y); r[6] = f2bf(b.z); r[7] = f2bf(b.w);
  return r;
}

// async global->LDS, 16B per lane, dest = uniform base + lane*16
__device__ __forceinline__ void gload16(const void* g, void* l) {
  __builtin_amdgcn_global_load_lds(
      (const __attribute__((address_space(1))) unsigned int*)g,
      (__attribute__((address_space(3))) unsigned int*)l, 16, 0, 0);
}

// ---------- prep: fp32 -> bf16 row-major (for K) ----------
__global__ void cvt_bf16(const float* __restrict__ in, ushort* __restrict__ ob, int n8) {
  int i = blockIdx.x * blockDim.x + threadIdx.x;
  if (i >= n8) return;
  const float4* p = (const float4*)(in + (size_t)i * 8);
  short8 v = pack8(p[0], p[1]);
  *(short8*)(ob + (size_t)i * 8) = v;
}

// ---------- prep: fp32 V (S x D) -> bf16 V^T (D x S) ----------
__global__ void transpose_bf16(const float* __restrict__ v, ushort* __restrict__ vt) {
  __shared__ float t[64][65];
  const int bs = blockIdx.x % (SEQ / 64);
  const int bd = blockIdx.x / (SEQ / 64);
  const int s0 = bs * 64, d0 = bd * 64;
  const int tid = threadIdx.x;
#pragma unroll
  for (int k = 0; k < 16; ++k) {
    int idx = k * 256 + tid;
    int r = idx >> 6, c = idx & 63;
    t[r][c] = v[(size_t)(s0 + r) * DIM + d0 + c];
  }
  __syncthreads();
#pragma unroll
  for (int k = 0; k < 16; ++k) {
    int idx = k * 256 + tid;
    int dr = idx >> 6, sc = idx & 63;
    vt[(size_t)(d0 + dr) * SEQ + s0 + sc] = (ushort)f2bf(t[sc][dr]);
  }
}

// ---------- fused attention: 2 blocks/CU, K/V LDS-staged, counted vmcnt ----------
// Wave roles (w = 0..7):
//   QK: rg=w&1 (16 q-rows), kg=(w>>1)&1 (16 keys), dh=w>>2 (D-half partial)
//   PV: rg=w&1 (16 q-rows), cg=w>>1 (128 out cols)
__global__ __launch_bounds__(512, 4) void attn_split(
    const float* __restrict__ q, const ushort* __restrict__ kbf,
    const ushort* __restrict__ vt, float* __restrict__ opart,
    float* __restrict__ ml) {
  __shared__ __align__(16) ushort kt[KVBLK * DIM];    // 32 KB, chunk ^= row&31
  __shared__ __align__(16) ushort vtt[DIM * KVBLK];   // 32 KB, 16B-granule ^= (row>>1)&3
  __shared__ float s_part[2][BQ][36];                 // 9.2 KB, QK partials per D-half
  __shared__ __align__(16) ushort p_lds[BQ * KVBLK];  // 2 KB, granule ^= (row>>1)&3
  __shared__ float m_st[BQ], l_st[BQ], osc_st[BQ];

  const int tid  = threadIdx.x;
  const int lane = tid & 63;
  const int w    = tid >> 6;
  const int lr   = lane & 15;
  const int lg   = lane >> 4;
  const int sp   = blockIdx.x & (SPLITS - 1);
  const int qb   = blockIdx.x >> 2;
  const int rg   = w & 1;
  const int kg   = (w >> 1) & 1;
  const int dh   = w >> 2;
  const int cg   = w >> 1;   // PV col-group (0..3)
  const int qrow0 = qb * BQ;
  const int kbase = sp * KEYS_PER_SPLIT;

  if (tid < BQ) { m_st[tid] = -INFINITY; l_st[tid] = 0.f; }

  // Q fragments: rows rg*16+lr, D-half dh (8 chunks of 32)
  short8 qf[8];
  {
    const float* qp = q + (size_t)(qrow0 + rg * 16 + lr) * DIM + dh * 256 + lg * 8;
#pragma unroll
    for (int c = 0; c < 8; ++c)
      qf[c] = pack8(*(const float4*)(qp + c * 32), *(const float4*)(qp + c * 32 + 4));
  }
  f32x4 oacc[8] = {};

  // K rows 1KB: LDS[r][ch] = K[kb+r][ch ^ (r&31)]; 4 gloads/wave
  auto stageK = [&](int kb) {
#pragma unroll
    for (int i = 0; i < 4; ++i) {
      int r = w * 4 + i;
      const ushort* src = kbf + (size_t)(kb + r) * DIM + ((lane ^ (r & 31)) * 8);
      gload16(src, &kt[r * DIM]);
    }
  };
  // V^T rows 64B (4 granules of 16B): granule g stored at g ^ ((row>>1)&3)
  auto stageV = [&](int kb) {
#pragma unroll
    for (int j = 0; j < 4; ++j) {
      int r0 = w * 64 + j * 16;
      int rr = r0 + (lane >> 2);
      int c16 = lane & 3;
      const ushort* src = vt + (size_t)rr * SEQ + kb + ((c16 ^ ((rr >> 1) & 3)) * 8);
      gload16(src, &vtt[r0 * KVBLK]);
    }
  };

  stageK(kbase);  // K(0) in flight

#pragma unroll 1
  for (int it = 0; it < ITERS; ++it) {
    const int kb = kbase + it * KVBLK;

    stageV(kb);  // V(t) in flight; lands during QK/softmax
    asm volatile("s_waitcnt vmcnt(4)" ::: "memory");  // K(t) landed (V(t)=4 out)
    __builtin_amdgcn_s_barrier();                     // bar-a

    // ---- QK^T partial: rows rg*16.., keys kg*16.., D-half dh ----
    {
      const int r0k = kg * 16 + lr;
      const char* krow = (const char*)kt + r0k * 1024;
      const int sw = r0k & 31;
      f32x4 sa = {}, sb = {};
      __builtin_amdgcn_s_setprio(1);
#pragma unroll
      for (int c = 0; c < 8; c += 2) {
        short8 k0 = *(const short8*)(krow + (((dh * 32 + c * 4 + lg) ^ sw) << 4));
        short8 k1 = *(const short8*)(krow + (((dh * 32 + (c + 1) * 4 + lg) ^ sw) << 4));
        sa = __builtin_amdgcn_mfma_f32_16x16x32_bf16(qf[c], k0, sa, 0, 0, 0);
        sb = __builtin_amdgcn_mfma_f32_16x16x32_bf16(qf[c + 1], k1, sb, 0, 0, 0);
      }
      __builtin_amdgcn_s_setprio(0);
#pragma unroll
      for (int r = 0; r < 4; ++r)
        s_part[dh][rg * 16 + lg * 4 + r][kg * 16 + lr] = sa[r] + sb[r];
    }
    asm volatile("s_waitcnt lgkmcnt(0)" ::: "memory");
    __builtin_amdgcn_s_barrier();                       // bar-b

    // ---- online softmax: 16 lanes/row, 2 keys/lane; sum D-half partials ----
    {
      const int srow = tid >> 4;
      const int sjl  = tid & 15;
      float2 a = *(const float2*)&s_part[0][srow][sjl * 2];
      float2 b = *(const float2*)&s_part[1][srow][sjl * 2];
      float s0 = (a.x + b.x) * SCALE;
      float s1 = (a.y + b.y) * SCALE;
      float tmax = fmaxf(s0, s1);
#pragma unroll
      for (int m = 1; m <= 8; m <<= 1) tmax = fmaxf(tmax, __shfl_xor(tmax, m));
      float mold = m_st[srow];
      float mnew = fmaxf(mold, tmax);
      float p0 = __expf(s0 - mnew), p1 = __expf(s1 - mnew);
      float ps = p0 + p1;
#pragma unroll
      for (int m = 1; m <= 8; m <<= 1) ps += __shfl_xor(ps, m);
      if (sjl == 0) {
        float sc = __expf(mold - mnew);
        osc_st[srow] = sc;
        l_st[srow] = l_st[srow] * sc + ps;
        m_st[srow] = mnew;
      }
      ushort2 pb;
      pb.x = (unsigned short)f2bf(p0);
      pb.y = (unsigned short)f2bf(p1);
      int ba = srow * 64 + ((sjl * 4) ^ (((srow >> 1) & 3) << 4));
      *(ushort2*)((char*)p_lds + ba) = pb;
    }

    if (it + 1 < ITERS) {
      stageK(kb + KVBLK);  // K(t+1) in flight; lands during PV
      asm volatile("s_waitcnt vmcnt(4)" ::: "memory");  // V(t) landed
    } else {
      asm volatile("s_waitcnt vmcnt(0)" ::: "memory");  // drain V(t) (no prefetch)
    }
    asm volatile("s_waitcnt lgkmcnt(0)" ::: "memory");  // p/m/l/osc visible
    __builtin_amdgcn_s_barrier();                       // bar-c

    // ---- rescale O, PV: rows rg*16.., cols cg*128.. ----
    {
      float osc[4];
#pragma unroll
      for (int r = 0; r < 4; ++r) osc[r] = osc_st[rg * 16 + lg * 4 + r];
#pragma unroll
      for (int ct = 0; ct < 8; ++ct)
#pragma unroll
        for (int r = 0; r < 4; ++r) oacc[ct][r] *= osc[r];

      const int prow = rg * 16 + lr;
      short8 pf = *(const short8*)((const char*)p_lds + prow * 64 +
                                   ((lg ^ ((prow >> 1) & 3)) << 4));
      const int D0 = cg * 128 + lr;
      const char* vbase = (const char*)vtt + D0 * 64 + ((lg ^ ((D0 >> 1) & 3)) << 4);
      __builtin_amdgcn_s_setprio(1);
#pragma unroll
      for (int ct = 0; ct < 8; ++ct) {
        short8 vf = *(const short8*)(vbase + ct * 1024);
        oacc[ct] = __builtin_amdgcn_mfma_f32_16x16x32_bf16(pf, vf, oacc[ct], 0, 0, 0);
      }
      __builtin_amdgcn_s_setprio(0);
    }
    asm volatile("s_waitcnt lgkmcnt(0)" ::: "memory");  // vtt/p reads complete
    __builtin_amdgcn_s_barrier();                       // bar-d: vtt free
  }

  // ---- epilogue: unnormalized partial O + (m,l) ----
  {
    float* op = opart + ((size_t)sp * SEQ + qrow0 + rg * 16) * DIM + cg * 128;
#pragma unroll
    for (int ct = 0; ct < 8; ++ct)
#pragma unroll
      for (int r = 0; r < 4; ++r)
        op[(size_t)(lg * 4 + r) * DIM + ct * 16 + lr] = oacc[ct][r];
    if (tid < BQ) {
      size_t base = ((size_t)sp * SEQ + qrow0 + tid) * 2;
      ml[base]     = m_st[tid];
      ml[base + 1] = l_st[tid];
    }
  }
}

// ---------- combine split partials ----------
__global__ void combine(const float* __restrict__ opart, const float* __restrict__ ml,
                        float* __restrict__ out) {
  int gid = blockIdx.x * 256 + threadIdx.x;
  int row = gid >> 7;
  int dv  = (gid & 127) * 4;
  float m[SPLITS], l[SPLITS], wgt[SPLITS];
  float M = -INFINITY;
#pragma unroll
  for (int i = 0; i < SPLITS; ++i) {
    m[i] = ml[((size_t)i * SEQ + row) * 2];
    l[i] = ml[((size_t)i * SEQ + row) * 2 + 1];
    M = fmaxf(M, m[i]);
  }
  float L = 0.f;
#pragma unroll
  for (int i = 0; i < SPLITS; ++i) { wgt[i] = __expf(m[i] - M); L += l[i] * wgt[i]; }
  float inv = 1.f / L;
  float4 acc = {0.f, 0.f, 0.f, 0.f};
#pragma unroll
  for (int i = 0; i < SPLITS; ++i) {
    float4 o = *(const float4*)(opart + ((size_t)i * SEQ + row) * DIM + dv);
    acc.x += o.x * wgt[i]; acc.y += o.y * wgt[i];
    acc.z += o.z * wgt[i]; acc.w += o.w * wgt[i];
  }
  acc.x *= inv; acc.y *= inv; acc.z *= inv; acc.w *= inv;
  *(float4*)(out + (size_t)row * DIM + dv) = acc;
}

// ---------- fallback if ws too small ----------
__global__ __launch_bounds__(512) void attn_fused_fb(
    const float* __restrict__ q, const float* __restrict__ k,
    const float* __restrict__ v, float* __restrict__ out) {
  __shared__ float s_lds[16][128];
  __shared__ __align__(16) unsigned short p_lds[16 * 128];
  __shared__ float m_st[16], l_st[16], osc_st[16];
  const int tid = threadIdx.x, lane = tid & 63, w = tid >> 6;
  const int lr = lane & 15, lg = lane >> 4, qb = blockIdx.x * 16;
  if (tid < 16) { m_st[tid] = -INFINITY; l_st[tid] = 0.f; }
  short8 qf[16];
  {
    const float* qp = q + (size_t)(qb + lr) * DIM + lg * 8;
#pragma unroll
    for (int c = 0; c < 16; ++c)
      qf[c] = pack8(*(const float4*)(qp + c * 32), *(const float4*)(qp + c * 32 + 4));
  }
  f32x4 oacc[4] = {};
  __syncthreads();
  for (int it = 0; it < SEQ / 128; ++it) {
    const int kb = it * 128;
    {
      const float* kp = k + (size_t)(kb + w * 16 + lr) * DIM + lg * 8;
      f32x4 sacc = {};
#pragma unroll
      for (int c = 0; c < 16; ++c) {
        short8 kf = pack8(*(const float4*)(kp + c * 32), *(const float4*)(kp + c * 32 + 4));
        sacc = __builtin_amdgcn_mfma_f32_16x16x32_bf16(qf[c], kf, sacc, 0, 0, 0);
      }
#pragma unroll
      for (int r = 0; r < 4; ++r) s_lds[lg * 4 + r][w * 16 + lr] = sacc[r] * SCALE;
    }
    __syncthreads();
    {
      const int srow = tid >> 5, sj = tid & 31;
      float4 sv = *(const float4*)&s_lds[srow][sj * 4];
      float tmax = fmaxf(fmaxf(sv.x, sv.y), fmaxf(sv.z, sv.w));
#pragma unroll
      for (int m = 16; m >= 1; m >>= 1) tmax = fmaxf(tmax, __shfl_xor(tmax, m));
      float mold = m_st[srow], mnew = fmaxf(mold, tmax);
      float p0 = __expf(sv.x - mnew), p1 = __expf(sv.y - mnew);
      float p2 = __expf(sv.z - mnew), p3 = __expf(sv.w - mnew);
      float psum = (p0 + p1) + (p2 + p3);
#pragma unroll
      for (int m = 16; m >= 1; m >>= 1) psum += __shfl_xor(psum, m);
      if (sj == 0) {
        float sc = __expf(mold - mnew);
        l_st[srow] = l_st[srow] * sc + psum; m_st[srow] = mnew; osc_st[srow] = sc;
      }
      ushort4 pb;
      pb.x = (unsigned short)f2bf(p0); pb.y = (unsigned short)f2bf(p1);
      pb.z = (unsigned short)f2bf(p2); pb.w = (unsigned short)f2bf(p3);
      int lin = srow * 256 + sj * 8;
      *(ushort4*)((char*)p_lds + (lin ^ ((srow & 7) << 4))) = pb;
    }
    __syncthreads();
    {
      float osc[4];
#pragma unroll
      for (int r = 0; r < 4; ++r) osc[r] = osc_st[lg * 4 + r];
#pragma unroll
      for (int ct = 0; ct < 4; ++ct)
#pragma unroll
        for (int r = 0; r < 4; ++r) oacc[ct][r] *= osc[r];
#pragma unroll
      for (int kc = 0; kc < 4; ++kc) {
        int lin = lr * 256 + (kc * 32 + 8 * lg) * 2;
        short8 pf = *(const short8*)((const char*)p_lds + (lin ^ ((lr & 7) << 4)));
        const float* vp0 = v + (size_t)(kb + kc * 32 + 8 * lg) * DIM + w * 64 + lr;
#pragma unroll
        for (int ct = 0; ct < 4; ++ct) {
          const float* vp = vp0 + ct * 16;
          short8 vf;
#pragma unroll
          for (int jj = 0; jj < 8; ++jj) vf[jj] = f2bf(vp[(size_t)jj * DIM]);
          oacc[ct] = __builtin_amdgcn_mfma_f32_16x16x32_bf16(pf, vf, oacc[ct], 0, 0, 0);
        }
      }
    }
    __syncthreads();
  }
  {
    float linv[4];
#pragma unroll
    for (int r = 0; r < 4; ++r) linv[r] = 1.f / l_st[lg * 4 + r];
#pragma unroll
    for (int ct = 0; ct < 4; ++ct)
#pragma unroll
      for (int r = 0; r < 4; ++r)
        out[(size_t)(qb + lg * 4 + r) * DIM + w * 64 + ct * 16 + lr] =
            oacc[ct][r] * linv[r];
  }
}

extern "C" void kernel_launch(void* const* d_in, const int* in_sizes, int n_in,
                              void* d_out, int out_size, void* d_ws, size_t ws_size,
                              hipStream_t stream) {
  (void)in_sizes; (void)n_in; (void)out_size;
  const float* q = (const float*)d_in[0];
  const float* k = (const float*)d_in[1];
  const float* v = (const float*)d_in[2];
  float* out = (float*)d_out;

  const size_t kbf_elems = (size_t)SEQ * DIM;
  const size_t vt_elems  = (size_t)DIM * SEQ;
  const size_t op_elems  = (size_t)SPLITS * SEQ * DIM;
  const size_t ml_elems  = (size_t)SPLITS * SEQ * 2;
  const size_t need = kbf_elems * 2 + vt_elems * 2 + op_elems * 4 + ml_elems * 4;

  if (ws_size >= need) {
    ushort* kbf  = (ushort*)d_ws;
    ushort* vtb  = kbf + kbf_elems;
    float* opart = (float*)(vtb + vt_elems);
    float* ml    = opart + op_elems;

    cvt_bf16<<<(SEQ * DIM / 8 + 255) / 256, 256, 0, stream>>>(k, kbf, SEQ * DIM / 8);
    transpose_bf16<<<(SEQ / 64) * (DIM / 64), 256, 0, stream>>>(v, vtb);
    attn_split<<<(SEQ / BQ) * SPLITS, 512, 0, stream>>>(q, kbf, vtb, opart, ml);
    combine<<<(SEQ * DIM / 4) / 256, 256, 0, stream>>>(opart, ml, out);
  } else {
    attn_fused_fb<<<SEQ / 16, 512, 0, stream>>>(q, k, v, out);
  }
}